// Round 14
// baseline (179.532 us; speedup 1.0000x reference)
//
#include <hip/hip_runtime.h>

#define T_ 12
#define N_ 1370
#define MSEQ 32      // sequences per block
#define LDA 72       // h LDS row stride in shorts (144B -> 2-way banks max)
#define NBLK 2740    // 87680 / 32

typedef __attribute__((ext_vector_type(4))) short short4v;
typedef __attribute__((ext_vector_type(8))) short short8;
typedef __attribute__((ext_vector_type(4))) float floatx4;

#define NLOG2E -1.4426950408889634f
#define TLOG2E 2.8853900817779268f
#define N2LOG2E -5.7707801635558536f   // -2*TLOG2E

__device__ __forceinline__ short f2bf(float x) {
  unsigned u = __builtin_bit_cast(unsigned, x);
  u = (u + 0x7fffu + ((u >> 16) & 1u)) >> 16;
  return (short)u;
}
// HW packed f32->bf16: low16 = bf16(a), high16 = bf16(b)
__device__ __forceinline__ unsigned pk_bf16(float a, float b) {
  unsigned r;
  asm("v_cvt_pk_bf16_f32 %0, %1, %2" : "=v"(r) : "v"(a), "v"(b));
  return r;
}
__device__ __forceinline__ short8 load_w8s(const float* __restrict__ p, float s) {
  short8 r;
#pragma unroll
  for (int j = 0; j < 8; ++j) r[j] = f2bf(p[j] * s);
  return r;
}
__device__ __forceinline__ short4v load_w4s(const float* __restrict__ p, float s) {
  short4v r;
#pragma unroll
  for (int j = 0; j < 4; ++j) r[j] = f2bf(p[j] * s);
  return r;
}

__device__ __forceinline__ floatx4 mfma16(short4v a, short4v b, floatx4 c) {
#if __has_builtin(__builtin_amdgcn_mfma_f32_16x16x16bf16_1k)
  return __builtin_amdgcn_mfma_f32_16x16x16bf16_1k(a, b, c, 0, 0, 0);
#elif __has_builtin(__builtin_amdgcn_mfma_f32_16x16x16_bf16)
  return __builtin_amdgcn_mfma_f32_16x16x16_bf16(a, b, c, 0, 0, 0);
#else
  asm volatile("v_mfma_f32_16x16x16_bf16 %0, %1, %2, %0\n\ts_nop 7\n\ts_nop 7"
               : "+v"(c)
               : "v"(a), "v"(b));
  return c;
#endif
}

// R13 body (passing, 100us, VGPR=60) with a targeted register diet to cross
// the 48-VGPR residency threshold (session law: pool ~192 VGPR/SIMD, so
// <=48 -> 4 waves/SIMD vs the current 3; occupancy flat for 56..64):
//   1. wAx (8 persistent VGPR) parked in LDS wxl[4][256] -- each thread
//      reads ONLY its own slot (no barrier needed; same-thread ds program
//      order). Laundered pointer per t (R6-proven) stops LICM re-hoisting.
//   2. bx addressing hoisted to base+stride (no per-t cndmask chains).
//   3. __launch_bounds__(256,5): allocator cap 256/5=51 -> granule 48.
//      (R9's disaster forced 40 on a 64-reg body; this forces ~48 on ~50.)
// LDS 23.6KB -> 6 blocks/CU cap >= the 4 blocks the VGPR law admits.
// Numerics identical (absmax 1.953e-3): weights pre-scaled (i,f,o by
// -log2e, g by 2*log2e), k16 x/bias chunk (R3/R6-verified layout),
// grouped reciprocals, cell state pre-scaled by 2*log2e.
__global__ void __launch_bounds__(256, 5) lstm_kernel(
    const float* __restrict__ x, const float* __restrict__ W_ih,
    const float* __restrict__ W_hh, const float* __restrict__ b_ih,
    const float* __restrict__ b_hh, const float* __restrict__ W_fc,
    const float* __restrict__ b_fc, float* __restrict__ out) {
  __shared__ short hbuf[2][MSEQ][LDA];                 // 9216 B
  __shared__ __align__(16) short xbuf[T_][MSEQ][8];    // 6144 B
  __shared__ __align__(16) short onesz[8];             // {1.0,0..} + zeros
  __shared__ short4v wxl[4][256];                      // 8192 B: parked wAx

  const int tid = threadIdx.x;
  const int wave = tid >> 6;
  const int lane = tid & 63;
  const int m16 = lane & 15;
  const int q = lane >> 4;
  const int blk = blockIdx.x;

  // ---- A-operand weight fragments: lane row = unit wave*16+m16 ----
  const int urow = wave * 16 + m16;
  short8 wAh[4][2];   // k=32 h-chunks (32 VGPR, persistent)
#pragma unroll
  for (int g = 0; g < 4; ++g) {
    const float sg = (g == 2) ? TLOG2E : NLOG2E;
    const int grow = g * 64 + urow;
    const float* wr = W_hh + grow * 64;
    wAh[g][0] = load_w8s(wr + q * 8, sg);
    wAh[g][1] = load_w8s(wr + 32 + q * 8, sg);
    short4v xv = {0, 0, 0, 0};
    if (q < 2) {
      xv = load_w4s(W_ih + grow * 8 + q * 4, sg);   // k=q*4+j: x cols 0..7
    } else if (q == 2) {
      xv[0] = f2bf(sg * (b_ih[grow] + b_hh[grow]));  // k=8: bias column
    }
    wxl[g][tid] = xv;   // park in LDS; re-read per t (own slot only)
  }

  // ---- zero hbuf (h0 = 0, pads = 0); onesz row for bias/zero B-lanes ----
  {
    int* hp = (int*)hbuf;
#pragma unroll
    for (int i = tid; i < (2 * MSEQ * LDA) / 2; i += 256) hp[i] = 0;
    if (tid < 8) onesz[tid] = (tid == 0) ? (short)0x3F80 : (short)0;
  }
  __syncthreads();

  // ---- stage all 12 timesteps of x as bf16 (compact 16B rows) ----
  {
    const int xseq = tid >> 3, xc = tid & 7;
    const int s0 = blk * MSEQ + xseq;
    const int bidx = s0 / N_;
    const int nidx = s0 - bidx * N_;
    const float* xp = x + ((size_t)(bidx * T_) * N_ + nidx) * 8 + xc;
#pragma unroll
    for (int t = 0; t < T_; ++t)
      xbuf[t][xseq][xc] = f2bf(xp[(size_t)t * (N_ * 8)]);
  }
  __syncthreads();

  const floatx4 zacc = {0.0f, 0.0f, 0.0f, 0.0f};

  float cst[2][4];
#pragma unroll
  for (int nt = 0; nt < 2; ++nt)
#pragma unroll
    for (int r = 0; r < 4; ++r) cst[nt][r] = 0.0f;

  // ---- hoisted bx addressing: base + t*stride, no per-t cndmask ----
  const short* bxb[2];
  const int bxstride = (q < 2) ? (MSEQ * 8) : 0;   // shorts per t step
#pragma unroll
  for (int nt = 0; nt < 2; ++nt) {
    const int srow = nt * 16 + m16;
    bxb[nt] = (q < 2) ? &xbuf[0][srow][q * 4] : &onesz[(q - 2) * 4];
  }

  // Laundered park-table pointer: loop-variant to the compiler so the 4
  // fragments are re-read from LDS each t instead of living in VGPRs.
  const short4v(*wxp)[256] = wxl;

  for (int t = 0; t < T_; ++t) {
    const int rb = t & 1, wb = rb ^ 1;
    asm("" : "+v"(wxp));   // optimization barrier: zero cost

    // ---- phase 1: all LDS reads ----
    short8 b0[2], b1[2];
    short4v bx[2];
#pragma unroll
    for (int nt = 0; nt < 2; ++nt) {
      const int srow = nt * 16 + m16;
      b0[nt] = *(const short8*)&hbuf[rb][srow][q * 8];
      b1[nt] = *(const short8*)&hbuf[rb][srow][32 + q * 8];
      bx[nt] = *(const short4v*)(bxb[nt] + (size_t)t * bxstride);
    }
    short4v wax[4];
#pragma unroll
    for (int g = 0; g < 4; ++g) wax[g] = wxp[g][tid];

    // ---- phase 2: all 24 MFMAs into materialized accumulators ----
    floatx4 acc[2][4];
#pragma unroll
    for (int nt = 0; nt < 2; ++nt)
#pragma unroll
      for (int g = 0; g < 4; ++g) {
        floatx4 c = __builtin_amdgcn_mfma_f32_16x16x32_bf16(wAh[g][0], b0[nt], zacc, 0, 0, 0);
        c = __builtin_amdgcn_mfma_f32_16x16x32_bf16(wAh[g][1], b1[nt], c, 0, 0, 0);
        c = mfma16(wax[g], bx[nt], c);
        acc[nt][g] = c;
      }

    // ---- phase 3a: all 32 gate exp2 (independent, stream the trans pipe)
    float di[2][4], df[2][4], dgv[2][4], dqv[2][4];
#pragma unroll
    for (int nt = 0; nt < 2; ++nt)
#pragma unroll
      for (int r = 0; r < 4; ++r) {
        di[nt][r] = 1.0f + __builtin_amdgcn_exp2f(acc[nt][0][r]);
        df[nt][r] = 1.0f + __builtin_amdgcn_exp2f(acc[nt][1][r]);
        dgv[nt][r] = 1.0f + __builtin_amdgcn_exp2f(acc[nt][2][r]);
        dqv[nt][r] = 1.0f + __builtin_amdgcn_exp2f(acc[nt][3][r]);
      }

    // ---- phase 3b: grouped rp across the nt pair (4 rcp instead of 8)
    float pa[2][4], pb[2][4], rp[2][4];
#pragma unroll
    for (int r = 0; r < 4; ++r) {
      pa[0][r] = di[0][r] * df[0][r];
      pb[0][r] = dgv[0][r] * dqv[0][r];
      pa[1][r] = di[1][r] * df[1][r];
      pb[1][r] = dgv[1][r] * dqv[1][r];
      const float PA = pa[0][r] * pb[0][r];
      const float PB = pa[1][r] * pb[1][r];
      const float R = __builtin_amdgcn_rcpf(PA * PB);
      rp[0][r] = R * PB;
      rp[1][r] = R * PA;
    }

    // ---- phase 3c: gate algebra + cell update + tanh-denominator exp2
    float ov[2][4], dt[2][4];
#pragma unroll
    for (int nt = 0; nt < 2; ++nt)
#pragma unroll
      for (int r = 0; r < 4; ++r) {
        const float fv = rp[nt][r] * di[nt][r] * pb[nt][r];      // f = 1/df
        ov[nt][r] = rp[nt][r] * pa[nt][r] * dgv[nt][r];          // o = 1/dq
        const float tg = fmaf(TLOG2E, dgv[nt][r], N2LOG2E);      // (dg-2)*2log2e
        const float ig = tg * rp[nt][r] * (df[nt][r] * dqv[nt][r]);
        const float cs = fmaf(fv, cst[nt][r], ig);               // c*2log2e
        cst[nt][r] = cs;
        dt[nt][r] = 1.0f + __builtin_amdgcn_exp2f(cs);
      }

    // ---- phase 3d: grouped tanh reciprocal per nt (1 rcp for 4 cells)
    unsigned long long pkv[2];
#pragma unroll
    for (int nt = 0; nt < 2; ++nt) {
      const float m01 = dt[nt][0] * dt[nt][1];
      const float m23 = dt[nt][2] * dt[nt][3];
      const float R = __builtin_amdgcn_rcpf(m01 * m23);
      const float r01 = R * m23, r23 = R * m01;
      float rdt[4];
      rdt[0] = r01 * dt[nt][1];
      rdt[1] = r01 * dt[nt][0];
      rdt[2] = r23 * dt[nt][3];
      rdt[3] = r23 * dt[nt][2];
      float hv[4];
#pragma unroll
      for (int r = 0; r < 4; ++r) {
        const float tw = ov[nt][r] + ov[nt][r];                  // 2*o
        hv[r] = fmaf(-tw, rdt[r], ov[nt][r]);                    // o*(1-2/dt)
      }
      pkv[nt] = (unsigned long long)pk_bf16(hv[0], hv[1]) |
                ((unsigned long long)pk_bf16(hv[2], hv[3]) << 32);
    }

    // ---- phase 4: h writes + barrier ----
#pragma unroll
    for (int nt = 0; nt < 2; ++nt) {
      const int srow = nt * 16 + m16;
      *(unsigned long long*)&hbuf[wb][srow][wave * 16 + q * 4] = pkv[nt];
    }
    __syncthreads();
  }

  // ---- final FC: y = h_T @ W_fc^T + b_fc; h_T is in hbuf[0] ----
  if (wave < 2) {
    short8 f0, f1;
    short8 z = {0, 0, 0, 0, 0, 0, 0, 0};
    if (m16 < 8) {
      const float* wr = W_fc + m16 * 64;
      f0 = load_w8s(wr + q * 8, 1.0f);
      f1 = load_w8s(wr + 32 + q * 8, 1.0f);
    } else {
      f0 = z;
      f1 = z;
    }
    const int srow = wave * 16 + m16;
    short8 h0 = *(const short8*)&hbuf[0][srow][q * 8];
    short8 h1 = *(const short8*)&hbuf[0][srow][32 + q * 8];
    floatx4 acc = __builtin_amdgcn_mfma_f32_16x16x32_bf16(f0, h0, zacc, 0, 0, 0);
    acc = __builtin_amdgcn_mfma_f32_16x16x32_bf16(f1, h1, acc, 0, 0, 0);
    if (q < 2) {
      const int orow = blk * MSEQ + srow;
#pragma unroll
      for (int r = 0; r < 4; ++r)
        out[orow * 8 + q * 4 + r] = acc[r] + b_fc[q * 4 + r];
    }
  }
}

extern "C" void kernel_launch(void* const* d_in, const int* in_sizes, int n_in,
                              void* d_out, int out_size, void* d_ws,
                              size_t ws_size, hipStream_t stream) {
  const float* x    = (const float*)d_in[0];
  const float* W_ih = (const float*)d_in[1];
  const float* W_hh = (const float*)d_in[2];
  const float* b_ih = (const float*)d_in[3];
  const float* b_hh = (const float*)d_in[4];
  const float* W_fc = (const float*)d_in[5];
  const float* b_fc = (const float*)d_in[6];
  float* out = (float*)d_out;
  hipLaunchKernelGGL(lstm_kernel, dim3(NBLK), dim3(256), 0, stream,
                     x, W_ih, W_hh, b_ih, b_hh, W_fc, b_fc, out);
}

// Round 15
// 179.360 us; speedup vs baseline: 1.0010x; 1.0010x over previous
//
#include <hip/hip_runtime.h>

#define T_ 12
#define N_ 1370
#define MSEQ 32      // sequences per block
#define LDA 72       // h LDS row stride in shorts (144B -> 2-way banks max)
#define NBLK 2740    // 87680 / 32

typedef __attribute__((ext_vector_type(4))) short short4v;
typedef __attribute__((ext_vector_type(8))) short short8;
typedef __attribute__((ext_vector_type(4))) float floatx4;

#define NLOG2E -1.4426950408889634f
#define TLOG2E 2.8853900817779268f
#define N2LOG2E -5.7707801635558536f   // -2*TLOG2E

__device__ __forceinline__ short f2bf(float x) {
  unsigned u = __builtin_bit_cast(unsigned, x);
  u = (u + 0x7fffu + ((u >> 16) & 1u)) >> 16;
  return (short)u;
}
// HW packed f32->bf16: low16 = bf16(a), high16 = bf16(b)
__device__ __forceinline__ unsigned pk_bf16(float a, float b) {
  unsigned r;
  asm("v_cvt_pk_bf16_f32 %0, %1, %2" : "=v"(r) : "v"(a), "v"(b));
  return r;
}
__device__ __forceinline__ short8 load_w8s(const float* __restrict__ p, float s) {
  short8 r;
#pragma unroll
  for (int j = 0; j < 8; ++j) r[j] = f2bf(p[j] * s);
  return r;
}
__device__ __forceinline__ short4v load_w4s(const float* __restrict__ p, float s) {
  short4v r;
#pragma unroll
  for (int j = 0; j < 4; ++j) r[j] = f2bf(p[j] * s);
  return r;
}

__device__ __forceinline__ floatx4 mfma16(short4v a, short4v b, floatx4 c) {
#if __has_builtin(__builtin_amdgcn_mfma_f32_16x16x16bf16_1k)
  return __builtin_amdgcn_mfma_f32_16x16x16bf16_1k(a, b, c, 0, 0, 0);
#elif __has_builtin(__builtin_amdgcn_mfma_f32_16x16x16_bf16)
  return __builtin_amdgcn_mfma_f32_16x16x16_bf16(a, b, c, 0, 0, 0);
#else
  asm volatile("v_mfma_f32_16x16x16_bf16 %0, %1, %2, %0\n\ts_nop 7\n\ts_nop 7"
               : "+v"(c)
               : "v"(a), "v"(b));
  return c;
#endif
}

// R14 (VGPR=48, occ 45% -- law confirmed) minus the spill: the (256,5) cap
// forced ~3 regs of scratch (WRITE 2.7->42.6MB, +19us). This round golfs
// ~8 transient regs so the body FITS under the 51-cap with zero spill:
//   1. no wax[4] array: phase 2 is g-outer/nt-inner; each parked fragment
//      wxp[g][tid] is read once per g where it feeds both nt MFMAs.
//   2. pkv written immediately per nt (no pkv[2] carry across phase 3d;
//      writes go to hbuf[wb], unread until the barrier -> safe).
// Else identical to R13/R14: wAx parked in LDS (laundered ptr), hoisted bx
// addressing, batched activation, grouped reciprocals, weights pre-scaled
// (i,f,o by -log2e, g by 2*log2e), cell state pre-scaled by 2*log2e.
// DECISIVE READ: no-spill + 48 VGPR + ~45% occ -> does the 4th wave/SIMD
// raise VALUBusy past ~63%? If not, trans-saturation is the roofline.
__global__ void __launch_bounds__(256, 5) lstm_kernel(
    const float* __restrict__ x, const float* __restrict__ W_ih,
    const float* __restrict__ W_hh, const float* __restrict__ b_ih,
    const float* __restrict__ b_hh, const float* __restrict__ W_fc,
    const float* __restrict__ b_fc, float* __restrict__ out) {
  __shared__ short hbuf[2][MSEQ][LDA];                 // 9216 B
  __shared__ __align__(16) short xbuf[T_][MSEQ][8];    // 6144 B
  __shared__ __align__(16) short onesz[8];             // {1.0,0..} + zeros
  __shared__ short4v wxl[4][256];                      // 8192 B: parked wAx

  const int tid = threadIdx.x;
  const int wave = tid >> 6;
  const int lane = tid & 63;
  const int m16 = lane & 15;
  const int q = lane >> 4;
  const int blk = blockIdx.x;

  // ---- A-operand weight fragments: lane row = unit wave*16+m16 ----
  const int urow = wave * 16 + m16;
  short8 wAh[4][2];   // k=32 h-chunks (32 VGPR, persistent)
#pragma unroll
  for (int g = 0; g < 4; ++g) {
    const float sg = (g == 2) ? TLOG2E : NLOG2E;
    const int grow = g * 64 + urow;
    const float* wr = W_hh + grow * 64;
    wAh[g][0] = load_w8s(wr + q * 8, sg);
    wAh[g][1] = load_w8s(wr + 32 + q * 8, sg);
    short4v xv = {0, 0, 0, 0};
    if (q < 2) {
      xv = load_w4s(W_ih + grow * 8 + q * 4, sg);   // k=q*4+j: x cols 0..7
    } else if (q == 2) {
      xv[0] = f2bf(sg * (b_ih[grow] + b_hh[grow]));  // k=8: bias column
    }
    wxl[g][tid] = xv;   // park in LDS; re-read per t (own slot only)
  }

  // ---- zero hbuf (h0 = 0, pads = 0); onesz row for bias/zero B-lanes ----
  {
    int* hp = (int*)hbuf;
#pragma unroll
    for (int i = tid; i < (2 * MSEQ * LDA) / 2; i += 256) hp[i] = 0;
    if (tid < 8) onesz[tid] = (tid == 0) ? (short)0x3F80 : (short)0;
  }
  __syncthreads();

  // ---- stage all 12 timesteps of x as bf16 (compact 16B rows) ----
  {
    const int xseq = tid >> 3, xc = tid & 7;
    const int s0 = blk * MSEQ + xseq;
    const int bidx = s0 / N_;
    const int nidx = s0 - bidx * N_;
    const float* xp = x + ((size_t)(bidx * T_) * N_ + nidx) * 8 + xc;
#pragma unroll
    for (int t = 0; t < T_; ++t)
      xbuf[t][xseq][xc] = f2bf(xp[(size_t)t * (N_ * 8)]);
  }
  __syncthreads();

  const floatx4 zacc = {0.0f, 0.0f, 0.0f, 0.0f};

  float cst[2][4];
#pragma unroll
  for (int nt = 0; nt < 2; ++nt)
#pragma unroll
    for (int r = 0; r < 4; ++r) cst[nt][r] = 0.0f;

  // ---- hoisted bx addressing: base + t*stride, no per-t cndmask ----
  const short* bxb[2];
  const int bxstride = (q < 2) ? (MSEQ * 8) : 0;   // shorts per t step
#pragma unroll
  for (int nt = 0; nt < 2; ++nt) {
    const int srow = nt * 16 + m16;
    bxb[nt] = (q < 2) ? &xbuf[0][srow][q * 4] : &onesz[(q - 2) * 4];
  }

  // Laundered park-table pointer: loop-variant to the compiler so the 4
  // fragments are re-read from LDS each t instead of living in VGPRs.
  const short4v(*wxp)[256] = wxl;

  for (int t = 0; t < T_; ++t) {
    const int rb = t & 1, wb = rb ^ 1;
    asm("" : "+v"(wxp));   // optimization barrier: zero cost

    // ---- phase 1: all LDS reads ----
    short8 b0[2], b1[2];
    short4v bx[2];
#pragma unroll
    for (int nt = 0; nt < 2; ++nt) {
      const int srow = nt * 16 + m16;
      b0[nt] = *(const short8*)&hbuf[rb][srow][q * 8];
      b1[nt] = *(const short8*)&hbuf[rb][srow][32 + q * 8];
      bx[nt] = *(const short4v*)(bxb[nt] + (size_t)t * bxstride);
    }

    // ---- phase 2: all 24 MFMAs, g-outer so each parked fragment is read
    // once and feeds both nt tiles (2 transient regs, not 8) ----
    floatx4 acc[2][4];
#pragma unroll
    for (int g = 0; g < 4; ++g) {
      const short4v wax = wxp[g][tid];
#pragma unroll
      for (int nt = 0; nt < 2; ++nt) {
        floatx4 c = __builtin_amdgcn_mfma_f32_16x16x32_bf16(wAh[g][0], b0[nt], zacc, 0, 0, 0);
        c = __builtin_amdgcn_mfma_f32_16x16x32_bf16(wAh[g][1], b1[nt], c, 0, 0, 0);
        c = mfma16(wax, bx[nt], c);
        acc[nt][g] = c;
      }
    }

    // ---- phase 3a: all 32 gate exp2 (independent, stream the trans pipe)
    float di[2][4], df[2][4], dgv[2][4], dqv[2][4];
#pragma unroll
    for (int nt = 0; nt < 2; ++nt)
#pragma unroll
      for (int r = 0; r < 4; ++r) {
        di[nt][r] = 1.0f + __builtin_amdgcn_exp2f(acc[nt][0][r]);
        df[nt][r] = 1.0f + __builtin_amdgcn_exp2f(acc[nt][1][r]);
        dgv[nt][r] = 1.0f + __builtin_amdgcn_exp2f(acc[nt][2][r]);
        dqv[nt][r] = 1.0f + __builtin_amdgcn_exp2f(acc[nt][3][r]);
      }

    // ---- phase 3b: grouped rp across the nt pair (4 rcp instead of 8)
    float pa[2][4], pb[2][4], rp[2][4];
#pragma unroll
    for (int r = 0; r < 4; ++r) {
      pa[0][r] = di[0][r] * df[0][r];
      pb[0][r] = dgv[0][r] * dqv[0][r];
      pa[1][r] = di[1][r] * df[1][r];
      pb[1][r] = dgv[1][r] * dqv[1][r];
      const float PA = pa[0][r] * pb[0][r];
      const float PB = pa[1][r] * pb[1][r];
      const float R = __builtin_amdgcn_rcpf(PA * PB);
      rp[0][r] = R * PB;
      rp[1][r] = R * PA;
    }

    // ---- phase 3c+3d per nt: gate algebra, cell update, grouped tanh
    // reciprocal, pack, IMMEDIATE h write (no pkv carry) ----
#pragma unroll
    for (int nt = 0; nt < 2; ++nt) {
      float ov[4], dt[4];
#pragma unroll
      for (int r = 0; r < 4; ++r) {
        const float fv = rp[nt][r] * di[nt][r] * pb[nt][r];      // f = 1/df
        ov[r] = rp[nt][r] * pa[nt][r] * dgv[nt][r];              // o = 1/dq
        const float tg = fmaf(TLOG2E, dgv[nt][r], N2LOG2E);      // (dg-2)*2log2e
        const float ig = tg * rp[nt][r] * (df[nt][r] * dqv[nt][r]);
        const float cs = fmaf(fv, cst[nt][r], ig);               // c*2log2e
        cst[nt][r] = cs;
        dt[r] = 1.0f + __builtin_amdgcn_exp2f(cs);
      }
      const float m01 = dt[0] * dt[1];
      const float m23 = dt[2] * dt[3];
      const float R = __builtin_amdgcn_rcpf(m01 * m23);
      const float r01 = R * m23, r23 = R * m01;
      float rdt[4];
      rdt[0] = r01 * dt[1];
      rdt[1] = r01 * dt[0];
      rdt[2] = r23 * dt[3];
      rdt[3] = r23 * dt[2];
      float hv[4];
#pragma unroll
      for (int r = 0; r < 4; ++r) {
        const float tw = ov[r] + ov[r];                          // 2*o
        hv[r] = fmaf(-tw, rdt[r], ov[r]);                        // o*(1-2/dt)
      }
      const unsigned long long pk =
          (unsigned long long)pk_bf16(hv[0], hv[1]) |
          ((unsigned long long)pk_bf16(hv[2], hv[3]) << 32);
      const int srow = nt * 16 + m16;
      *(unsigned long long*)&hbuf[wb][srow][wave * 16 + q * 4] = pk;
    }
    __syncthreads();
  }

  // ---- final FC: y = h_T @ W_fc^T + b_fc; h_T is in hbuf[0] ----
  if (wave < 2) {
    short8 f0, f1;
    short8 z = {0, 0, 0, 0, 0, 0, 0, 0};
    if (m16 < 8) {
      const float* wr = W_fc + m16 * 64;
      f0 = load_w8s(wr + q * 8, 1.0f);
      f1 = load_w8s(wr + 32 + q * 8, 1.0f);
    } else {
      f0 = z;
      f1 = z;
    }
    const int srow = wave * 16 + m16;
    short8 h0 = *(const short8*)&hbuf[0][srow][q * 8];
    short8 h1 = *(const short8*)&hbuf[0][srow][32 + q * 8];
    floatx4 acc = __builtin_amdgcn_mfma_f32_16x16x32_bf16(f0, h0, zacc, 0, 0, 0);
    acc = __builtin_amdgcn_mfma_f32_16x16x32_bf16(f1, h1, acc, 0, 0, 0);
    if (q < 2) {
      const int orow = blk * MSEQ + srow;
#pragma unroll
      for (int r = 0; r < 4; ++r)
        out[orow * 8 + q * 4 + r] = acc[r] + b_fc[q * 4 + r];
    }
  }
}

extern "C" void kernel_launch(void* const* d_in, const int* in_sizes, int n_in,
                              void* d_out, int out_size, void* d_ws,
                              size_t ws_size, hipStream_t stream) {
  const float* x    = (const float*)d_in[0];
  const float* W_ih = (const float*)d_in[1];
  const float* W_hh = (const float*)d_in[2];
  const float* b_ih = (const float*)d_in[3];
  const float* b_hh = (const float*)d_in[4];
  const float* W_fc = (const float*)d_in[5];
  const float* b_fc = (const float*)d_in[6];
  float* out = (float*)d_out;
  hipLaunchKernelGGL(lstm_kernel, dim3(NBLK), dim3(256), 0, stream,
                     x, W_ih, W_hh, b_ih, b_hh, W_fc, b_fc, out);
}

// Round 16
// 164.696 us; speedup vs baseline: 1.0901x; 1.0890x over previous
//
#include <hip/hip_runtime.h>

#define T_ 12
#define N_ 1370
#define MSEQ 32      // sequences per block
#define LDA 72       // h LDS row stride in shorts (144B -> 2-way banks max)
#define NBLK 2740    // 87680 / 32

typedef __attribute__((ext_vector_type(4))) short short4v;
typedef __attribute__((ext_vector_type(8))) short short8;
typedef __attribute__((ext_vector_type(4))) float floatx4;

#define NLOG2E -1.4426950408889634f
#define TLOG2E 2.8853900817779268f
#define N2LOG2E -5.7707801635558536f   // -2*TLOG2E

__device__ __forceinline__ short f2bf(float x) {
  unsigned u = __builtin_bit_cast(unsigned, x);
  u = (u + 0x7fffu + ((u >> 16) & 1u)) >> 16;
  return (short)u;
}
// HW packed f32->bf16: low16 = bf16(a), high16 = bf16(b)
__device__ __forceinline__ unsigned pk_bf16(float a, float b) {
  unsigned r;
  asm("v_cvt_pk_bf16_f32 %0, %1, %2" : "=v"(r) : "v"(a), "v"(b));
  return r;
}
__device__ __forceinline__ short8 load_w8s(const float* __restrict__ p, float s) {
  short8 r;
#pragma unroll
  for (int j = 0; j < 8; ++j) r[j] = f2bf(p[j] * s);
  return r;
}
__device__ __forceinline__ short4v load_w4s(const float* __restrict__ p, float s) {
  short4v r;
#pragma unroll
  for (int j = 0; j < 4; ++j) r[j] = f2bf(p[j] * s);
  return r;
}

__device__ __forceinline__ floatx4 mfma16(short4v a, short4v b, floatx4 c) {
#if __has_builtin(__builtin_amdgcn_mfma_f32_16x16x16bf16_1k)
  return __builtin_amdgcn_mfma_f32_16x16x16bf16_1k(a, b, c, 0, 0, 0);
#elif __has_builtin(__builtin_amdgcn_mfma_f32_16x16x16_bf16)
  return __builtin_amdgcn_mfma_f32_16x16x16_bf16(a, b, c, 0, 0, 0);
#else
  asm volatile("v_mfma_f32_16x16x16_bf16 %0, %1, %2, %0\n\ts_nop 7\n\ts_nop 7"
               : "+v"(c)
               : "v"(a), "v"(b));
  return c;
#endif
}

// Pressure-shaped variant: lesson of R9/R11/R14/R15 is that FORCING a VGPR
// cap always spills; the allocator must land <=48 naturally. The batched
// phase 3 (acc[2][4] + 32 gate-denoms live at once) drives the natural 60.
// Fix: per-nt processing with the rp grouping moved WITHIN nt across
// r-pairs (R01=rcp(P0*P1) -> rp0,rp1; R23 likewise; + 1 grouped tanh rcp)
// -- SAME 6 rcp/lane-t as R13, but nt=0's whole MFMA->act->write chain
// retires before nt=1 starts -> transient peak halves. wAx stays parked in
// LDS (laundered ptr, R13-proven). NO __launch_bounds__: worst case the
// allocator lands ~52-60 and we reproduce R13's 100us; if <=48, the
// session's residency law (pool ~192/SIMD) gives the 4th wave/SIMD.
// Numerics: same ops as R13 (absmax 1.953e-3) -- weights pre-scaled
// (i,f,o by -log2e, g by 2*log2e), cell state pre-scaled by 2*log2e,
// grouped reciprocals (regrouped, same rounding class).
__global__ void lstm_kernel(
    const float* __restrict__ x, const float* __restrict__ W_ih,
    const float* __restrict__ W_hh, const float* __restrict__ b_ih,
    const float* __restrict__ b_hh, const float* __restrict__ W_fc,
    const float* __restrict__ b_fc, float* __restrict__ out) {
  __shared__ short hbuf[2][MSEQ][LDA];                 // 9216 B
  __shared__ __align__(16) short xbuf[T_][MSEQ][8];    // 6144 B
  __shared__ __align__(16) short onesz[8];             // {1.0,0..} + zeros
  __shared__ short4v wxl[4][256];                      // 8192 B: parked wAx

  const int tid = threadIdx.x;
  const int wave = tid >> 6;
  const int lane = tid & 63;
  const int m16 = lane & 15;
  const int q = lane >> 4;
  const int blk = blockIdx.x;

  // ---- A-operand weight fragments: lane row = unit wave*16+m16 ----
  const int urow = wave * 16 + m16;
  short8 wAh[4][2];   // k=32 h-chunks (32 VGPR, persistent)
#pragma unroll
  for (int g = 0; g < 4; ++g) {
    const float sg = (g == 2) ? TLOG2E : NLOG2E;
    const int grow = g * 64 + urow;
    const float* wr = W_hh + grow * 64;
    wAh[g][0] = load_w8s(wr + q * 8, sg);
    wAh[g][1] = load_w8s(wr + 32 + q * 8, sg);
    short4v xv = {0, 0, 0, 0};
    if (q < 2) {
      xv = load_w4s(W_ih + grow * 8 + q * 4, sg);   // k=q*4+j: x cols 0..7
    } else if (q == 2) {
      xv[0] = f2bf(sg * (b_ih[grow] + b_hh[grow]));  // k=8: bias column
    }
    wxl[g][tid] = xv;   // park in LDS; re-read per t (own slot only)
  }

  // ---- zero hbuf (h0 = 0, pads = 0); onesz row for bias/zero B-lanes ----
  {
    int* hp = (int*)hbuf;
#pragma unroll
    for (int i = tid; i < (2 * MSEQ * LDA) / 2; i += 256) hp[i] = 0;
    if (tid < 8) onesz[tid] = (tid == 0) ? (short)0x3F80 : (short)0;
  }
  __syncthreads();

  // ---- stage all 12 timesteps of x as bf16 (compact 16B rows) ----
  {
    const int xseq = tid >> 3, xc = tid & 7;
    const int s0 = blk * MSEQ + xseq;
    const int bidx = s0 / N_;
    const int nidx = s0 - bidx * N_;
    const float* xp = x + ((size_t)(bidx * T_) * N_ + nidx) * 8 + xc;
#pragma unroll
    for (int t = 0; t < T_; ++t)
      xbuf[t][xseq][xc] = f2bf(xp[(size_t)t * (N_ * 8)]);
  }
  __syncthreads();

  const floatx4 zacc = {0.0f, 0.0f, 0.0f, 0.0f};

  float cst[2][4];
#pragma unroll
  for (int nt = 0; nt < 2; ++nt)
#pragma unroll
    for (int r = 0; r < 4; ++r) cst[nt][r] = 0.0f;

  // ---- hoisted bx addressing: one base + strides, no per-t cndmask ----
  const short* bx0 = (q < 2) ? &xbuf[0][m16][q * 4] : &onesz[(q - 2) * 4];
  const int bxt = (q < 2) ? (MSEQ * 8) : 0;   // shorts per t step
  const int bxnt = (q < 2) ? (16 * 8) : 0;    // shorts per nt step

  // Laundered park-table pointer: loop-variant to the compiler so the 4
  // fragments are re-read from LDS each t instead of living in VGPRs.
  const short4v(*wxp)[256] = wxl;

  for (int t = 0; t < T_; ++t) {
    const int rb = t & 1, wb = rb ^ 1;
    asm("" : "+v"(wxp));   // optimization barrier: zero cost

    // ---- per-nt: full MFMA -> activation -> write chain, then next nt ----
#pragma unroll
    for (int nt = 0; nt < 2; ++nt) {
      const int srow = nt * 16 + m16;
      const short8 b0 = *(const short8*)&hbuf[rb][srow][q * 8];
      const short8 b1 = *(const short8*)&hbuf[rb][srow][32 + q * 8];
      const short4v bx =
          *(const short4v*)(bx0 + (size_t)t * bxt + (size_t)nt * bxnt);

      floatx4 acc[4];
#pragma unroll
      for (int g = 0; g < 4; ++g) {
        floatx4 c = __builtin_amdgcn_mfma_f32_16x16x32_bf16(wAh[g][0], b0, zacc, 0, 0, 0);
        c = __builtin_amdgcn_mfma_f32_16x16x32_bf16(wAh[g][1], b1, c, 0, 0, 0);
        c = mfma16(wxp[g][tid], bx, c);
        acc[g] = c;
      }

      // all 16 gate exp2 for this nt (independent, stream the trans pipe)
      float di[4], df[4], dgv[4], dqv[4];
#pragma unroll
      for (int r = 0; r < 4; ++r) {
        di[r] = 1.0f + __builtin_amdgcn_exp2f(acc[0][r]);
        df[r] = 1.0f + __builtin_amdgcn_exp2f(acc[1][r]);
        dgv[r] = 1.0f + __builtin_amdgcn_exp2f(acc[2][r]);
        dqv[r] = 1.0f + __builtin_amdgcn_exp2f(acc[3][r]);
      }

      // grouped gate reciprocal across r-pairs: 2 rcp for 4 cells
      float pa[4], pb[4], rp[4];
#pragma unroll
      for (int r = 0; r < 4; ++r) {
        pa[r] = di[r] * df[r];
        pb[r] = dgv[r] * dqv[r];
      }
      {
        const float P0 = pa[0] * pb[0], P1 = pa[1] * pb[1];
        const float R01 = __builtin_amdgcn_rcpf(P0 * P1);
        rp[0] = R01 * P1;
        rp[1] = R01 * P0;
        const float P2 = pa[2] * pb[2], P3 = pa[3] * pb[3];
        const float R23 = __builtin_amdgcn_rcpf(P2 * P3);
        rp[2] = R23 * P3;
        rp[3] = R23 * P2;
      }

      // gate algebra + cell update + tanh-denominator exp2
      float ov[4], dt[4];
#pragma unroll
      for (int r = 0; r < 4; ++r) {
        const float fv = rp[r] * di[r] * pb[r];            // f = 1/df
        ov[r] = rp[r] * pa[r] * dgv[r];                    // o = 1/dq
        const float tg = fmaf(TLOG2E, dgv[r], N2LOG2E);    // (dg-2)*2log2e
        const float ig = tg * rp[r] * (df[r] * dqv[r]);    // i*g*2log2e
        const float cs = fmaf(fv, cst[nt][r], ig);         // c*2log2e
        cst[nt][r] = cs;
        dt[r] = 1.0f + __builtin_amdgcn_exp2f(cs);
      }

      // grouped tanh reciprocal: 1 rcp for 4 cells; pack; immediate write
      const float m01 = dt[0] * dt[1];
      const float m23 = dt[2] * dt[3];
      const float R = __builtin_amdgcn_rcpf(m01 * m23);
      const float r01 = R * m23, r23 = R * m01;
      float rdt[4];
      rdt[0] = r01 * dt[1];
      rdt[1] = r01 * dt[0];
      rdt[2] = r23 * dt[3];
      rdt[3] = r23 * dt[2];
      float hv[4];
#pragma unroll
      for (int r = 0; r < 4; ++r) {
        const float tw = ov[r] + ov[r];                    // 2*o
        hv[r] = fmaf(-tw, rdt[r], ov[r]);                  // o*(1-2/dt)
      }
      const unsigned long long pk =
          (unsigned long long)pk_bf16(hv[0], hv[1]) |
          ((unsigned long long)pk_bf16(hv[2], hv[3]) << 32);
      *(unsigned long long*)&hbuf[wb][srow][wave * 16 + q * 4] = pk;
    }
    __syncthreads();
  }

  // ---- final FC: y = h_T @ W_fc^T + b_fc; h_T is in hbuf[0] ----
  if (wave < 2) {
    short8 f0, f1;
    short8 z = {0, 0, 0, 0, 0, 0, 0, 0};
    if (m16 < 8) {
      const float* wr = W_fc + m16 * 64;
      f0 = load_w8s(wr + q * 8, 1.0f);
      f1 = load_w8s(wr + 32 + q * 8, 1.0f);
    } else {
      f0 = z;
      f1 = z;
    }
    const int srow = wave * 16 + m16;
    short8 h0 = *(const short8*)&hbuf[0][srow][q * 8];
    short8 h1 = *(const short8*)&hbuf[0][srow][32 + q * 8];
    floatx4 acc = __builtin_amdgcn_mfma_f32_16x16x32_bf16(f0, h0, zacc, 0, 0, 0);
    acc = __builtin_amdgcn_mfma_f32_16x16x32_bf16(f1, h1, acc, 0, 0, 0);
    if (q < 2) {
      const int orow = blk * MSEQ + srow;
#pragma unroll
      for (int r = 0; r < 4; ++r)
        out[orow * 8 + q * 4 + r] = acc[r] + b_fc[q * 4 + r];
    }
  }
}

extern "C" void kernel_launch(void* const* d_in, const int* in_sizes, int n_in,
                              void* d_out, int out_size, void* d_ws,
                              size_t ws_size, hipStream_t stream) {
  const float* x    = (const float*)d_in[0];
  const float* W_ih = (const float*)d_in[1];
  const float* W_hh = (const float*)d_in[2];
  const float* b_ih = (const float*)d_in[3];
  const float* b_hh = (const float*)d_in[4];
  const float* W_fc = (const float*)d_in[5];
  const float* b_fc = (const float*)d_in[6];
  float* out = (float*)d_out;
  hipLaunchKernelGGL(lstm_kernel, dim3(NBLK), dim3(256), 0, stream,
                     x, W_ih, W_hh, b_ih, b_hh, W_fc, b_fc, out);
}

// Round 17
// 162.828 us; speedup vs baseline: 1.1026x; 1.0115x over previous
//
#include <hip/hip_runtime.h>

#define T_ 12
#define N_ 1370
#define MSEQ 32      // sequences per block
#define LDA 72       // h LDS row stride in shorts (144B -> 2-way banks max)
#define NBLK 2740    // 87680 / 32

typedef __attribute__((ext_vector_type(4))) short short4v;
typedef __attribute__((ext_vector_type(8))) short short8;
typedef __attribute__((ext_vector_type(4))) float floatx4;

#define NLOG2E -1.4426950408889634f
#define TLOG2E 2.8853900817779268f
#define N2LOG2E -5.7707801635558536f   // -2*TLOG2E

__device__ __forceinline__ short f2bf(float x) {
  unsigned u = __builtin_bit_cast(unsigned, x);
  u = (u + 0x7fffu + ((u >> 16) & 1u)) >> 16;
  return (short)u;
}
// HW packed f32->bf16: low16 = bf16(a), high16 = bf16(b)
__device__ __forceinline__ unsigned pk_bf16(float a, float b) {
  unsigned r;
  asm("v_cvt_pk_bf16_f32 %0, %1, %2" : "=v"(r) : "v"(a), "v"(b));
  return r;
}
__device__ __forceinline__ short8 load_w8s(const float* __restrict__ p, float s) {
  short8 r;
#pragma unroll
  for (int j = 0; j < 8; ++j) r[j] = f2bf(p[j] * s);
  return r;
}
__device__ __forceinline__ short4v load_w4s(const float* __restrict__ p, float s) {
  short4v r;
#pragma unroll
  for (int j = 0; j < 4; ++j) r[j] = f2bf(p[j] * s);
  return r;
}

__device__ __forceinline__ floatx4 mfma16(short4v a, short4v b, floatx4 c) {
#if __has_builtin(__builtin_amdgcn_mfma_f32_16x16x16bf16_1k)
  return __builtin_amdgcn_mfma_f32_16x16x16bf16_1k(a, b, c, 0, 0, 0);
#elif __has_builtin(__builtin_amdgcn_mfma_f32_16x16x16_bf16)
  return __builtin_amdgcn_mfma_f32_16x16x16_bf16(a, b, c, 0, 0, 0);
#else
  asm volatile("v_mfma_f32_16x16x16_bf16 %0, %1, %2, %0\n\ts_nop 7\n\ts_nop 7"
               : "+v"(c)
               : "v"(a), "v"(b));
  return c;
#endif
}

// SESSION-BEST kernel (R13 verbatim): 100.0us kernel time, VGPR=60, zero
// spill, absmax 1.953e-3. Restored after R16's clean falsification of the
// residency->fill theory (VGPR=48 / occ 45% / no spill gave 108us, i.e.
// MORE waves did NOT raise fill past ~60%).
// Final bottleneck determination: trans-pipe + per-timestep critical path.
// Issue-work floor ~60us (46 trans x16cyc + ~190 VALU x2cyc per wave-t x
// 131520 wave-ts / 1024 SIMDs) == measured VALUBusy(63%) x dur. Not HBM
// (2.6%), not MFMA (21%), not occupancy (R16), not rcp count (R8), not
// barriers (R2/R6), not register pressure (R14/R15).
// Structure: 32 seqs/block, 4 waves; A = weights (m = gate unit), B =
// [h | x | 1] (n = seq); k=32 h-chunks in regs (wAh), k=16 x/bias chunk
// (wAx, R3/R6-verified layout: q0 x cols 0-3, q1 cols 4-7, q2 j0 bias);
// h double-buffered in LDS, one b64 write/lane/nt; weights pre-scaled
// (i,f,o by -log2e, g by 2*log2e), grouped reciprocals (nt-pair rp +
// per-nt tanh), cell state carried pre-scaled by 2*log2e.
__global__ void lstm_kernel(
    const float* __restrict__ x, const float* __restrict__ W_ih,
    const float* __restrict__ W_hh, const float* __restrict__ b_ih,
    const float* __restrict__ b_hh, const float* __restrict__ W_fc,
    const float* __restrict__ b_fc, float* __restrict__ out) {
  __shared__ short hbuf[2][MSEQ][LDA];                 // 9216 B
  __shared__ __align__(16) short xbuf[T_][MSEQ][8];    // 6144 B
  __shared__ __align__(16) short onesz[8];             // {1.0,0..} + zeros

  const int tid = threadIdx.x;
  const int wave = tid >> 6;
  const int lane = tid & 63;
  const int m16 = lane & 15;
  const int q = lane >> 4;
  const int blk = blockIdx.x;

  // ---- A-operand weight fragments: lane row = unit wave*16+m16 ----
  const int urow = wave * 16 + m16;
  short8 wAh[4][2];   // k=32 h-chunks (32 VGPR)
  short4v wAx[4];     // k=16 x/bias chunk (8 VGPR)
#pragma unroll
  for (int g = 0; g < 4; ++g) {
    const float sg = (g == 2) ? TLOG2E : NLOG2E;
    const int grow = g * 64 + urow;
    const float* wr = W_hh + grow * 64;
    wAh[g][0] = load_w8s(wr + q * 8, sg);
    wAh[g][1] = load_w8s(wr + 32 + q * 8, sg);
    short4v xv = {0, 0, 0, 0};
    if (q < 2) {
      xv = load_w4s(W_ih + grow * 8 + q * 4, sg);   // k=q*4+j: x cols 0..7
    } else if (q == 2) {
      xv[0] = f2bf(sg * (b_ih[grow] + b_hh[grow]));  // k=8: bias column
    }
    wAx[g] = xv;
  }

  // ---- zero hbuf (h0 = 0, pads = 0); onesz row for bias/zero B-lanes ----
  {
    int* hp = (int*)hbuf;
#pragma unroll
    for (int i = tid; i < (2 * MSEQ * LDA) / 2; i += 256) hp[i] = 0;
    if (tid < 8) onesz[tid] = (tid == 0) ? (short)0x3F80 : (short)0;
  }
  __syncthreads();

  // ---- stage all 12 timesteps of x as bf16 (compact 16B rows) ----
  {
    const int xseq = tid >> 3, xc = tid & 7;
    const int s0 = blk * MSEQ + xseq;
    const int bidx = s0 / N_;
    const int nidx = s0 - bidx * N_;
    const float* xp = x + ((size_t)(bidx * T_) * N_ + nidx) * 8 + xc;
#pragma unroll
    for (int t = 0; t < T_; ++t)
      xbuf[t][xseq][xc] = f2bf(xp[(size_t)t * (N_ * 8)]);
  }
  __syncthreads();

  const floatx4 zacc = {0.0f, 0.0f, 0.0f, 0.0f};

  float cst[2][4];
#pragma unroll
  for (int nt = 0; nt < 2; ++nt)
#pragma unroll
    for (int r = 0; r < 4; ++r) cst[nt][r] = 0.0f;

  for (int t = 0; t < T_; ++t) {
    const int rb = t & 1, wb = rb ^ 1;

    // ---- phase 1: all LDS reads ----
    short8 b0[2], b1[2];
    short4v bx[2];
#pragma unroll
    for (int nt = 0; nt < 2; ++nt) {
      const int srow = nt * 16 + m16;
      b0[nt] = *(const short8*)&hbuf[rb][srow][q * 8];
      b1[nt] = *(const short8*)&hbuf[rb][srow][32 + q * 8];
      // B k16 x-frag: q0/q1 -> x[q*4..q*4+3], q2 -> {1,0,0,0}, q3 -> 0
      const short* bxp = (q < 2) ? &xbuf[t][srow][q * 4] : &onesz[(q - 2) * 4];
      bx[nt] = *(const short4v*)bxp;
    }

    // ---- phase 2: all 24 MFMAs into materialized accumulators ----
    floatx4 acc[2][4];
#pragma unroll
    for (int nt = 0; nt < 2; ++nt)
#pragma unroll
      for (int g = 0; g < 4; ++g) {
        floatx4 c = __builtin_amdgcn_mfma_f32_16x16x32_bf16(wAh[g][0], b0[nt], zacc, 0, 0, 0);
        c = __builtin_amdgcn_mfma_f32_16x16x32_bf16(wAh[g][1], b1[nt], c, 0, 0, 0);
        c = mfma16(wAx[g], bx[nt], c);
        acc[nt][g] = c;
      }

    // ---- phase 3a: all 32 gate exp2 (independent, stream the trans pipe)
    float di[2][4], df[2][4], dgv[2][4], dqv[2][4];
#pragma unroll
    for (int nt = 0; nt < 2; ++nt)
#pragma unroll
      for (int r = 0; r < 4; ++r) {
        di[nt][r] = 1.0f + __builtin_amdgcn_exp2f(acc[nt][0][r]);
        df[nt][r] = 1.0f + __builtin_amdgcn_exp2f(acc[nt][1][r]);
        dgv[nt][r] = 1.0f + __builtin_amdgcn_exp2f(acc[nt][2][r]);
        dqv[nt][r] = 1.0f + __builtin_amdgcn_exp2f(acc[nt][3][r]);
      }

    // ---- phase 3b: grouped rp across the nt pair (4 rcp instead of 8)
    float pa[2][4], pb[2][4], rp[2][4];
#pragma unroll
    for (int r = 0; r < 4; ++r) {
      pa[0][r] = di[0][r] * df[0][r];
      pb[0][r] = dgv[0][r] * dqv[0][r];
      pa[1][r] = di[1][r] * df[1][r];
      pb[1][r] = dgv[1][r] * dqv[1][r];
      const float PA = pa[0][r] * pb[0][r];
      const float PB = pa[1][r] * pb[1][r];
      const float R = __builtin_amdgcn_rcpf(PA * PB);
      rp[0][r] = R * PB;
      rp[1][r] = R * PA;
    }

    // ---- phase 3c: gate algebra + cell update + tanh-denominator exp2
    float ov[2][4], dt[2][4];
#pragma unroll
    for (int nt = 0; nt < 2; ++nt)
#pragma unroll
      for (int r = 0; r < 4; ++r) {
        const float fv = rp[nt][r] * di[nt][r] * pb[nt][r];      // f = 1/df
        ov[nt][r] = rp[nt][r] * pa[nt][r] * dgv[nt][r];          // o = 1/dq
        const float tg = fmaf(TLOG2E, dgv[nt][r], N2LOG2E);      // (dg-2)*2log2e
        const float ig = tg * rp[nt][r] * (df[nt][r] * dqv[nt][r]);
        const float cs = fmaf(fv, cst[nt][r], ig);               // c*2log2e
        cst[nt][r] = cs;
        dt[nt][r] = 1.0f + __builtin_amdgcn_exp2f(cs);
      }

    // ---- phase 3d: grouped tanh reciprocal per nt (1 rcp for 4 cells)
    unsigned long long pkv[2];
#pragma unroll
    for (int nt = 0; nt < 2; ++nt) {
      const float m01 = dt[nt][0] * dt[nt][1];
      const float m23 = dt[nt][2] * dt[nt][3];
      const float R = __builtin_amdgcn_rcpf(m01 * m23);
      const float r01 = R * m23, r23 = R * m01;
      float rdt[4];
      rdt[0] = r01 * dt[nt][1];
      rdt[1] = r01 * dt[nt][0];
      rdt[2] = r23 * dt[nt][3];
      rdt[3] = r23 * dt[nt][2];
      float hv[4];
#pragma unroll
      for (int r = 0; r < 4; ++r) {
        const float tw = ov[nt][r] + ov[nt][r];                  // 2*o
        hv[r] = fmaf(-tw, rdt[r], ov[nt][r]);                    // o*(1-2/dt)
      }
      pkv[nt] = (unsigned long long)pk_bf16(hv[0], hv[1]) |
                ((unsigned long long)pk_bf16(hv[2], hv[3]) << 32);
    }

    // ---- phase 4: h writes + barrier ----
#pragma unroll
    for (int nt = 0; nt < 2; ++nt) {
      const int srow = nt * 16 + m16;
      *(unsigned long long*)&hbuf[wb][srow][wave * 16 + q * 4] = pkv[nt];
    }
    __syncthreads();
  }

  // ---- final FC: y = h_T @ W_fc^T + b_fc; h_T is in hbuf[0] ----
  if (wave < 2) {
    short8 f0, f1;
    short8 z = {0, 0, 0, 0, 0, 0, 0, 0};
    if (m16 < 8) {
      const float* wr = W_fc + m16 * 64;
      f0 = load_w8s(wr + q * 8, 1.0f);
      f1 = load_w8s(wr + 32 + q * 8, 1.0f);
    } else {
      f0 = z;
      f1 = z;
    }
    const int srow = wave * 16 + m16;
    short8 h0 = *(const short8*)&hbuf[0][srow][q * 8];
    short8 h1 = *(const short8*)&hbuf[0][srow][32 + q * 8];
    floatx4 acc = __builtin_amdgcn_mfma_f32_16x16x32_bf16(f0, h0, zacc, 0, 0, 0);
    acc = __builtin_amdgcn_mfma_f32_16x16x32_bf16(f1, h1, acc, 0, 0, 0);
    if (q < 2) {
      const int orow = blk * MSEQ + srow;
#pragma unroll
      for (int r = 0; r < 4; ++r)
        out[orow * 8 + q * 4 + r] = acc[r] + b_fc[q * 4 + r];
    }
  }
}

extern "C" void kernel_launch(void* const* d_in, const int* in_sizes, int n_in,
                              void* d_out, int out_size, void* d_ws,
                              size_t ws_size, hipStream_t stream) {
  const float* x    = (const float*)d_in[0];
  const float* W_ih = (const float*)d_in[1];
  const float* W_hh = (const float*)d_in[2];
  const float* b_ih = (const float*)d_in[3];
  const float* b_hh = (const float*)d_in[4];
  const float* W_fc = (const float*)d_in[5];
  const float* b_fc = (const float*)d_in[6];
  float* out = (float*)d_out;
  hipLaunchKernelGGL(lstm_kernel, dim3(NBLK), dim3(256), 0, stream,
                     x, W_ih, W_hh, b_ih, b_hh, W_fc, b_fc, out);
}